// Round 15
// baseline (41.678 us; speedup 1.0000x reference)
//
#include <hip/hip_runtime.h>

typedef float f32x4 __attribute__((ext_vector_type(4)));

// out[b][v][p][i][s] = shell[s]*sh[i] / norm[b][l(i)][s]
// B=8 V=2048 P=32 I=16 S=4, monoms=20
// k1: 2048 blk -> partials[2048][16]
// k3: slim LDS staging {n,sl}; consumption = ONE row per lane -> every store
//     instruction is a fully dense 1KB wave store (lane L -> base + L*16B).

__device__ __forceinline__ void compute_monoms(float nx, float ny, float nz, float* m) {
    float zp2 = nz*nz, zp3 = zp2*nz;
    float yp2 = ny*ny, yp3 = yp2*ny;
    float xp2 = nx*nx, xp3 = xp2*nx;
    m[0]=1.0f;  m[1]=nz;       m[2]=zp2;      m[3]=zp3;
    m[4]=ny;    m[5]=ny*nz;    m[6]=ny*zp2;
    m[7]=yp2;   m[8]=yp2*nz;   m[9]=yp3;
    m[10]=nx;   m[11]=nx*nz;   m[12]=nx*zp2;
    m[13]=nx*ny; m[14]=nx*ny*nz; m[15]=nx*yp2;
    m[16]=xp2;  m[17]=xp2*nz;  m[18]=xp2*ny;
    m[19]=xp3;
}

__device__ __forceinline__ void compute_shells(float dist, float* sl) {
    const float B1 = 32.0f/3.0f, B2 = 64.0f/3.0f, B3 = 32.0f;
    const float C1 = -16.0f/9.0f, C2 = -64.0f/9.0f, C3 = -16.0f;
    float nd2 = -16.0f * dist * dist;
    sl[0] = __expf(nd2);
    sl[1] = __expf(fmaf(B1, dist, nd2 + C1));
    sl[2] = __expf(fmaf(B2, dist, nd2 + C2));
    sl[3] = __expf(fmaf(B3, dist, nd2 + C3));
    float den = sl[0] + sl[1] + sl[2] + sl[3];
    float r = 1.0f / fmaxf(den, 1e-6f);
    float mask = (dist <= 1.0f) ? r : 0.0f;
#pragma unroll
    for (int s = 0; s < 4; ++s) sl[s] *= mask;
}

// ---------------- K1: 2048 blocks, 8 units -> block-sum -> partials[blk][16] ----------------
__global__ __launch_bounds__(256) void sh_k1(const float* __restrict__ patches,
                                             const float* __restrict__ Y,
                                             float* __restrict__ partials) {
    __shared__ float sh2_lds[8][32][17];
    __shared__ float shl2_lds[8][32][5];
    __shared__ float l2_lds[8][16][4];
    __shared__ float red[8][16];

    const int tid  = threadIdx.x;
    const int wv   = tid >> 6;
    const int lane = tid & 63;
    const int half = lane >> 5;
    const int p    = lane & 31;
    const int u    = wv * 2 + half;
    const int unit = blockIdx.x * 8 + u;

    const float* pp = patches + ((size_t)unit * 32 + p) * 3;
    float x = pp[0], y = pp[1], z = pp[2];
    float dist = sqrtf(x*x + y*y + z*z);
    float inv  = 1.0f / fmaxf(dist, 1e-6f);
    float nx = -x*inv, ny = -y*inv, nz = -z*inv;
    float m[20];
    compute_monoms(nx, ny, nz, m);

#pragma unroll
    for (int i = 0; i < 16; ++i) {
        float acc = 0.f;
#pragma unroll
        for (int j = 0; j < 20; ++j)
            acc = fmaf(Y[i*20 + j], m[j], acc);   // uniform -> s_load
        sh2_lds[u][p][i] = acc * acc;
    }
    float sl[4];
    compute_shells(dist, sl);
#pragma unroll
    for (int s = 0; s < 4; ++s) shl2_lds[u][p][s] = sl[s]*sl[s];
    __syncthreads();

    const int ri = lane >> 2, rs = lane & 3;
    const int u0 = wv*2, u1 = wv*2 + 1;
    float acc0 = 0.f, acc1 = 0.f;
#pragma unroll
    for (int q = 0; q < 32; ++q) {
        acc0 = fmaf(sh2_lds[u0][q][ri], shl2_lds[u0][q][rs], acc0);
        acc1 = fmaf(sh2_lds[u1][q][ri], shl2_lds[u1][q][rs], acc1);
    }
    l2_lds[u0][ri][rs] = acc0;
    l2_lds[u1][ri][rs] = acc1;
    __syncthreads();

    if (lane < 32) {
        const int h2 = lane >> 4;
        const int c  = lane & 15;            // c = l*4 + s
        const int l  = c >> 2, s = c & 3;
        const int uu = wv*2 + h2;
        const int start = l*l, cnt = 2*l + 1;
        float acc = 0.f;
        for (int t = 0; t < cnt; ++t) acc += l2_lds[uu][start + t][s];
        red[uu][c] = sqrtf(acc);
    }
    __syncthreads();
    if (tid < 16) {
        float s2 = 0.f;
#pragma unroll
        for (int uu = 0; uu < 8; ++uu) s2 += red[uu][tid];
        partials[blockIdx.x*16 + tid] = s2;   // deterministic, no atomics
    }
}

// ---------------- K3: slim staging + dense 1KB wave stores (1 row/lane) ----------------
__global__ __launch_bounds__(256) void sh_k3(const float* __restrict__ patches,
                                             const float* __restrict__ Y,
                                             const float* __restrict__ partials,
                                             f32x4* __restrict__ out) {
    __shared__ float mon[256][12];     // [0..2]=n, [4..7]=sl, stride 12
    __shared__ float pr[16][17];
    __shared__ float rcp_lds[16];

    const int tid = threadIdx.x;
    const int blk = blockIdx.x;        // 0..2047, 256 blocks per batch
    const int bb  = blk >> 8;          // batch

    // ---- issue partial loads EARLY (hide latency under production) ----
    const int ch = tid & 15, r0 = tid >> 4;   // r0 0..15
    float pl[16];
#pragma unroll
    for (int r = 0; r < 16; ++r)
        pl[r] = partials[((size_t)bb*256 + r0 + r*16)*16 + ch];

    // ---- production: thread t computes point blk*256+t once -> LDS (8 floats) ----
    {
        const size_t ptg = (size_t)blk*256 + tid;
        const float* pp = patches + ptg*3;
        float x = pp[0], y = pp[1], z = pp[2];
        float dist = sqrtf(x*x + y*y + z*z);
        float inv  = 1.0f / fmaxf(dist, 1e-6f);
        float sl[4];
        compute_shells(dist, sl);
        f32x4 n4 = { -x*inv, -y*inv, -z*inv, 0.f };
        f32x4 s4 = { sl[0], sl[1], sl[2], sl[3] };
        *(f32x4*)&mon[tid][0] = n4;
        *(f32x4*)&mon[tid][4] = s4;
    }
    // ---- fold partials ----
    {
        float a = 0.f;
#pragma unroll
        for (int r = 0; r < 16; ++r) a += pl[r];
        pr[r0][ch] = a;
    }
    __syncthreads();
    if (tid < 16) {
        float s = 0.f;
#pragma unroll
        for (int r = 0; r < 16; ++r) s += pr[r][tid];
        float meanv = s * (1.0f/2048.0f);
        rcp_lds[tid] = 1.0f / fmaxf(meanv, 1e-8f);
    }
    __syncthreads();

    // ---- consumption: lane -> (pgrp, i); each store = dense 1KB per wave ----
    const int i    = tid & 15;          // output row
    const int pgrp = tid >> 4;          // 0..15

    const float4* Y4 = (const float4*)Y;
    float yr[20];
#pragma unroll
    for (int q = 0; q < 5; ++q) {
        float4 t = Y4[i*5 + q];
        yr[q*4+0]=t.x; yr[q*4+1]=t.y; yr[q*4+2]=t.z; yr[q*4+3]=t.w;
    }
    const int l = (i == 0) ? 0 : ((i < 4) ? 1 : ((i < 9) ? 2 : 3));
    const float rc0=rcp_lds[l*4+0], rc1=rcp_lds[l*4+1], rc2=rcp_lds[l*4+2], rc3=rcp_lds[l*4+3];

#pragma unroll 2
    for (int it2 = 0; it2 < 16; ++it2) {
        const int r = it2*16 + pgrp;    // staged point row
        f32x4 n4 = *(const f32x4*)&mon[r][0];
        f32x4 s4 = *(const f32x4*)&mon[r][4];

        float m[20];
        compute_monoms(n4.x, n4.y, n4.z, m);

        float sh = 0.f;
#pragma unroll
        for (int j = 0; j < 20; ++j)
            sh = fmaf(yr[j], m[j], sh);

        const size_t pt = (size_t)blk*256 + r;
        f32x4 o;
        o.x = sh*s4.x*rc0;
        o.y = sh*s4.y*rc1;
        o.z = sh*s4.z*rc2;
        o.w = sh*s4.w*rc3;
        // addr = blk*64KB + it2*4KB + (pgrp*16 + i)*16B  ->  lane L -> +L*16B (dense)
        __builtin_nontemporal_store(o, &out[pt*16 + i]);
    }
}

extern "C" void kernel_launch(void* const* d_in, const int* in_sizes, int n_in,
                              void* d_out, int out_size, void* d_ws, size_t ws_size,
                              hipStream_t stream) {
    const float* patches = (const float*)d_in[0];   // 8*2048*32*3
    const float* Y       = (const float*)d_in[1];   // 16*20
    f32x4* out4 = (f32x4*)d_out;

    float* partials = (float*)d_ws;                 // 2048*16 floats = 128 KB

    sh_k1<<<2048, 256, 0, stream>>>(patches, Y, partials);
    sh_k3<<<2048, 256, 0, stream>>>(patches, Y, partials, out4);
}

// Round 16
// 36.967 us; speedup vs baseline: 1.1274x; 1.1274x over previous
//
#include <hip/hip_runtime.h>

typedef float f32x4 __attribute__((ext_vector_type(4)));

// out[b][v][p][i][s] = shell[s]*sh[i] / norm[b][l(i)][s]
// B=8 V=2048 P=32 I=16 S=4, monoms=20
// A/B ROUND: exact R15 structure; ONLY change = plain store instead of
// __builtin_nontemporal_store (nt-flag write-path isolation).

__device__ __forceinline__ void compute_monoms(float nx, float ny, float nz, float* m) {
    float zp2 = nz*nz, zp3 = zp2*nz;
    float yp2 = ny*ny, yp3 = yp2*ny;
    float xp2 = nx*nx, xp3 = xp2*nx;
    m[0]=1.0f;  m[1]=nz;       m[2]=zp2;      m[3]=zp3;
    m[4]=ny;    m[5]=ny*nz;    m[6]=ny*zp2;
    m[7]=yp2;   m[8]=yp2*nz;   m[9]=yp3;
    m[10]=nx;   m[11]=nx*nz;   m[12]=nx*zp2;
    m[13]=nx*ny; m[14]=nx*ny*nz; m[15]=nx*yp2;
    m[16]=xp2;  m[17]=xp2*nz;  m[18]=xp2*ny;
    m[19]=xp3;
}

__device__ __forceinline__ void compute_shells(float dist, float* sl) {
    const float B1 = 32.0f/3.0f, B2 = 64.0f/3.0f, B3 = 32.0f;
    const float C1 = -16.0f/9.0f, C2 = -64.0f/9.0f, C3 = -16.0f;
    float nd2 = -16.0f * dist * dist;
    sl[0] = __expf(nd2);
    sl[1] = __expf(fmaf(B1, dist, nd2 + C1));
    sl[2] = __expf(fmaf(B2, dist, nd2 + C2));
    sl[3] = __expf(fmaf(B3, dist, nd2 + C3));
    float den = sl[0] + sl[1] + sl[2] + sl[3];
    float r = 1.0f / fmaxf(den, 1e-6f);
    float mask = (dist <= 1.0f) ? r : 0.0f;
#pragma unroll
    for (int s = 0; s < 4; ++s) sl[s] *= mask;
}

// ---------------- K1: 2048 blocks, 8 units -> block-sum -> partials[blk][16] ----------------
__global__ __launch_bounds__(256) void sh_k1(const float* __restrict__ patches,
                                             const float* __restrict__ Y,
                                             float* __restrict__ partials) {
    __shared__ float sh2_lds[8][32][17];
    __shared__ float shl2_lds[8][32][5];
    __shared__ float l2_lds[8][16][4];
    __shared__ float red[8][16];

    const int tid  = threadIdx.x;
    const int wv   = tid >> 6;
    const int lane = tid & 63;
    const int half = lane >> 5;
    const int p    = lane & 31;
    const int u    = wv * 2 + half;
    const int unit = blockIdx.x * 8 + u;

    const float* pp = patches + ((size_t)unit * 32 + p) * 3;
    float x = pp[0], y = pp[1], z = pp[2];
    float dist = sqrtf(x*x + y*y + z*z);
    float inv  = 1.0f / fmaxf(dist, 1e-6f);
    float nx = -x*inv, ny = -y*inv, nz = -z*inv;
    float m[20];
    compute_monoms(nx, ny, nz, m);

#pragma unroll
    for (int i = 0; i < 16; ++i) {
        float acc = 0.f;
#pragma unroll
        for (int j = 0; j < 20; ++j)
            acc = fmaf(Y[i*20 + j], m[j], acc);   // uniform -> s_load
        sh2_lds[u][p][i] = acc * acc;
    }
    float sl[4];
    compute_shells(dist, sl);
#pragma unroll
    for (int s = 0; s < 4; ++s) shl2_lds[u][p][s] = sl[s]*sl[s];
    __syncthreads();

    const int ri = lane >> 2, rs = lane & 3;
    const int u0 = wv*2, u1 = wv*2 + 1;
    float acc0 = 0.f, acc1 = 0.f;
#pragma unroll
    for (int q = 0; q < 32; ++q) {
        acc0 = fmaf(sh2_lds[u0][q][ri], shl2_lds[u0][q][rs], acc0);
        acc1 = fmaf(sh2_lds[u1][q][ri], shl2_lds[u1][q][rs], acc1);
    }
    l2_lds[u0][ri][rs] = acc0;
    l2_lds[u1][ri][rs] = acc1;
    __syncthreads();

    if (lane < 32) {
        const int h2 = lane >> 4;
        const int c  = lane & 15;            // c = l*4 + s
        const int l  = c >> 2, s = c & 3;
        const int uu = wv*2 + h2;
        const int start = l*l, cnt = 2*l + 1;
        float acc = 0.f;
        for (int t = 0; t < cnt; ++t) acc += l2_lds[uu][start + t][s];
        red[uu][c] = sqrtf(acc);
    }
    __syncthreads();
    if (tid < 16) {
        float s2 = 0.f;
#pragma unroll
        for (int uu = 0; uu < 8; ++uu) s2 += red[uu][tid];
        partials[blockIdx.x*16 + tid] = s2;   // deterministic, no atomics
    }
}

// ---------------- K3: slim staging + dense 1KB wave stores (1 row/lane), PLAIN stores ------
__global__ __launch_bounds__(256) void sh_k3(const float* __restrict__ patches,
                                             const float* __restrict__ Y,
                                             const float* __restrict__ partials,
                                             f32x4* __restrict__ out) {
    __shared__ float mon[256][12];     // [0..2]=n, [4..7]=sl, stride 12
    __shared__ float pr[16][17];
    __shared__ float rcp_lds[16];

    const int tid = threadIdx.x;
    const int blk = blockIdx.x;        // 0..2047, 256 blocks per batch
    const int bb  = blk >> 8;          // batch

    // ---- issue partial loads EARLY (hide latency under production) ----
    const int ch = tid & 15, r0 = tid >> 4;   // r0 0..15
    float pl[16];
#pragma unroll
    for (int r = 0; r < 16; ++r)
        pl[r] = partials[((size_t)bb*256 + r0 + r*16)*16 + ch];

    // ---- production: thread t computes point blk*256+t once -> LDS (8 floats) ----
    {
        const size_t ptg = (size_t)blk*256 + tid;
        const float* pp = patches + ptg*3;
        float x = pp[0], y = pp[1], z = pp[2];
        float dist = sqrtf(x*x + y*y + z*z);
        float inv  = 1.0f / fmaxf(dist, 1e-6f);
        float sl[4];
        compute_shells(dist, sl);
        f32x4 n4 = { -x*inv, -y*inv, -z*inv, 0.f };
        f32x4 s4 = { sl[0], sl[1], sl[2], sl[3] };
        *(f32x4*)&mon[tid][0] = n4;
        *(f32x4*)&mon[tid][4] = s4;
    }
    // ---- fold partials ----
    {
        float a = 0.f;
#pragma unroll
        for (int r = 0; r < 16; ++r) a += pl[r];
        pr[r0][ch] = a;
    }
    __syncthreads();
    if (tid < 16) {
        float s = 0.f;
#pragma unroll
        for (int r = 0; r < 16; ++r) s += pr[r][tid];
        float meanv = s * (1.0f/2048.0f);
        rcp_lds[tid] = 1.0f / fmaxf(meanv, 1e-8f);
    }
    __syncthreads();

    // ---- consumption: lane -> (pgrp, i); each store = dense 1KB per wave ----
    const int i    = tid & 15;          // output row
    const int pgrp = tid >> 4;          // 0..15

    const float4* Y4 = (const float4*)Y;
    float yr[20];
#pragma unroll
    for (int q = 0; q < 5; ++q) {
        float4 t = Y4[i*5 + q];
        yr[q*4+0]=t.x; yr[q*4+1]=t.y; yr[q*4+2]=t.z; yr[q*4+3]=t.w;
    }
    const int l = (i == 0) ? 0 : ((i < 4) ? 1 : ((i < 9) ? 2 : 3));
    const float rc0=rcp_lds[l*4+0], rc1=rcp_lds[l*4+1], rc2=rcp_lds[l*4+2], rc3=rcp_lds[l*4+3];

#pragma unroll 2
    for (int it2 = 0; it2 < 16; ++it2) {
        const int r = it2*16 + pgrp;    // staged point row
        f32x4 n4 = *(const f32x4*)&mon[r][0];
        f32x4 s4 = *(const f32x4*)&mon[r][4];

        float m[20];
        compute_monoms(n4.x, n4.y, n4.z, m);

        float sh = 0.f;
#pragma unroll
        for (int j = 0; j < 20; ++j)
            sh = fmaf(yr[j], m[j], sh);

        const size_t pt = (size_t)blk*256 + r;
        f32x4 o;
        o.x = sh*s4.x*rc0;
        o.y = sh*s4.y*rc1;
        o.z = sh*s4.z*rc2;
        o.w = sh*s4.w*rc3;
        // A/B: PLAIN store (R15 identical except this line)
        out[pt*16 + i] = o;
    }
}

extern "C" void kernel_launch(void* const* d_in, const int* in_sizes, int n_in,
                              void* d_out, int out_size, void* d_ws, size_t ws_size,
                              hipStream_t stream) {
    const float* patches = (const float*)d_in[0];   // 8*2048*32*3
    const float* Y       = (const float*)d_in[1];   // 16*20
    f32x4* out4 = (f32x4*)d_out;

    float* partials = (float*)d_ws;                 // 2048*16 floats = 128 KB

    sh_k1<<<2048, 256, 0, stream>>>(patches, Y, partials);
    sh_k3<<<2048, 256, 0, stream>>>(patches, Y, partials, out4);
}